// Round 8
// baseline (9990.173 us; speedup 1.0000x reference)
//
#include <hip/hip_runtime.h>
#include <hip/hip_fp16.h>

typedef _Float16 f16x8 __attribute__((ext_vector_type(8)));
typedef float f32x4 __attribute__((ext_vector_type(4)));
typedef unsigned int u32x4 __attribute__((ext_vector_type(4)));
typedef unsigned int u32x2 __attribute__((ext_vector_type(2)));

static constexpr int T_SEQ = 512;
static constexpr int BATCH = 64;
static constexpr int HID   = 512;
static constexpr int VOC   = 128;

// ---- fp16 arena element offsets ----
static constexpr int AOFF_EMB  = 0;        // 128*256
static constexpr int AOFF_WXH0 = 32768;    // 512*256
static constexpr int AOFF_WHH0 = 163840;   // 512*512
static constexpr int AOFF_WXH1 = 425984;   // 512*512
static constexpr int AOFF_WHH1 = 688128;   // 512*512
static constexpr int AOFF_WHY  = 950272;   // 128*512
static constexpr int ATOT      = 1015808;

// ---- ws byte offsets ----
static constexpr size_t OFF_FLAGS = 0;                    // 16 regions * 64 ints
static constexpr size_t OFF_RING  = 4096;                 // 2 layers * 65536 u32
static constexpr size_t OFF_ARENA = 532480;
static constexpr size_t PLANE_B   = (size_t)T_SEQ * BATCH * HID * 2;  // 32 MB
static constexpr size_t OFF_XW0   = 4u << 20;
static constexpr size_t OFF_XW1   = OFF_XW0 + PLANE_B;
static constexpr size_t OFF_H0P   = OFF_XW1 + PLANE_B;
static constexpr size_t OFF_H1P   = OFF_H0P + PLANE_B;    // ends ~132 MB

__device__ __forceinline__ unsigned short h2u(_Float16 h) {
  union { _Float16 h; unsigned short u; } c; c.h = h; return c.u;
}
__device__ __forceinline__ _Float16 u2h(unsigned short u) {
  union { unsigned short u; _Float16 h; } c; c.u = u; return c.h;
}
__device__ __forceinline__ float fast_tanh(float x) {
  float e = __expf(2.0f * x);
  return 1.0f - 2.0f * __builtin_amdgcn_rcpf(e + 1.0f);
}

// fp32 params -> fp16 arena; zero flags.
__global__ __launch_bounds__(256) void canon_kernel(
    const float* p0, const float* p1, const float* p2, const float* p3,
    const float* p4, const float* p5, _Float16* __restrict__ dst,
    int* __restrict__ flags) {
  if (blockIdx.x == 0)
    for (int i = threadIdx.x; i < 16 * 64; i += 256) flags[i] = 0;
  const float* srcs[6] = {p0, p1, p2, p3, p4, p5};
  const int ns[6] = {32768, 131072, 262144, 262144, 262144, 65536};
  for (int i = blockIdx.x * 256 + threadIdx.x; i < ATOT; i += gridDim.x * 256) {
    int off = i, s = 0;
    while (off >= ns[s]) { off -= ns[s]; ++s; }
    dst[i] = (_Float16)srcs[s][off];
  }
}

// xwf0[t][n][b] = emb[x[b,t]][:] . Wxh0[n][:] + bh0[n].  Grid (512, 8) x 256.
__global__ __launch_bounds__(256) void xw0_kernel(
    const int* __restrict__ x, const _Float16* __restrict__ emb,
    const _Float16* __restrict__ Wxh, const float* __restrict__ bh,
    _Float16* __restrict__ xwf) {
  __shared__ _Float16 Bs[64][264];
  const int t = blockIdx.x, n0 = blockIdx.y * 64, tid = threadIdx.x;
#pragma unroll
  for (int rep = 0; rep < 8; ++rep) {
    int flat = rep * 256 + tid;
    int row = flat >> 5, c8 = flat & 31;
    *(f16x8*)&Bs[row][c8 * 8] = *(const f16x8*)&Wxh[(size_t)(n0 + row) * 256 + c8 * 8];
  }
  __syncthreads();
  const int wv = tid >> 6, lane = tid & 63, l15 = lane & 15, quad = lane >> 4;
  const int b = wv * 16 + l15;
  const int idx = x[b * 512 + t];
  f32x4 acc[4];
#pragma unroll
  for (int nt = 0; nt < 4; ++nt) { float bv = bh[n0 + nt * 16 + l15]; acc[nt] = {bv, bv, bv, bv}; }
#pragma unroll
  for (int kc = 0; kc < 8; ++kc) {
    f16x8 a = *(const f16x8*)&emb[(size_t)idx * 256 + kc * 32 + quad * 8];
#pragma unroll
    for (int nt = 0; nt < 4; ++nt) {
      f16x8 bf = *(const f16x8*)&Bs[nt * 16 + l15][kc * 32 + quad * 8];
      acc[nt] = __builtin_amdgcn_mfma_f32_16x16x32_f16(a, bf, acc[nt], 0, 0, 0);
    }
  }
#pragma unroll
  for (int nt = 0; nt < 4; ++nt) {
    unsigned int lo = (unsigned int)h2u((_Float16)acc[nt][0]) |
                      ((unsigned int)h2u((_Float16)acc[nt][1]) << 16);
    unsigned int hi = (unsigned int)h2u((_Float16)acc[nt][2]) |
                      ((unsigned int)h2u((_Float16)acc[nt][3]) << 16);
    u32x2 pk = {lo, hi};
    *(u32x2*)&xwf[(size_t)t * 32768 + (size_t)(n0 + nt * 16 + l15) * 64 + wv * 16 + quad * 4] = pk;
  }
}

// xwf1[t][n][b] = h0[t*64+b][:] . Wxh1[n][:] + bh1[n].  Grid (512, 16) x 256.
__global__ __launch_bounds__(256) void xw1_kernel(
    const _Float16* __restrict__ hin, const _Float16* __restrict__ Wxh,
    const float* __restrict__ bh, _Float16* __restrict__ xwf) {
  __shared__ _Float16 Bs[32][520];
  const int t = blockIdx.x, n0 = blockIdx.y * 32, tid = threadIdx.x;
#pragma unroll
  for (int rep = 0; rep < 8; ++rep) {
    int flat = rep * 256 + tid;
    int row = flat >> 6, c8 = flat & 63;
    *(f16x8*)&Bs[row][c8 * 8] = *(const f16x8*)&Wxh[(size_t)(n0 + row) * 512 + c8 * 8];
  }
  __syncthreads();
  const int wv = tid >> 6, lane = tid & 63, l15 = lane & 15, quad = lane >> 4;
  const int m = t * 64 + wv * 16 + l15;
  f32x4 acc[2];
#pragma unroll
  for (int nt = 0; nt < 2; ++nt) { float bv = bh[n0 + nt * 16 + l15]; acc[nt] = {bv, bv, bv, bv}; }
#pragma unroll
  for (int kc = 0; kc < 16; ++kc) {
    f16x8 a = *(const f16x8*)&hin[(size_t)m * 512 + kc * 32 + quad * 8];
#pragma unroll
    for (int nt = 0; nt < 2; ++nt) {
      f16x8 bf = *(const f16x8*)&Bs[nt * 16 + l15][kc * 32 + quad * 8];
      acc[nt] = __builtin_amdgcn_mfma_f32_16x16x32_f16(a, bf, acc[nt], 0, 0, 0);
    }
  }
#pragma unroll
  for (int nt = 0; nt < 2; ++nt) {
    unsigned int lo = (unsigned int)h2u((_Float16)acc[nt][0]) |
                      ((unsigned int)h2u((_Float16)acc[nt][1]) << 16);
    unsigned int hi = (unsigned int)h2u((_Float16)acc[nt][2]) |
                      ((unsigned int)h2u((_Float16)acc[nt][3]) << 16);
    u32x2 pk = {lo, hi};
    *(u32x2*)&xwf[(size_t)t * 32768 + (size_t)(n0 + nt * 16 + l15) * 64 + wv * 16 + quad * 4] = pk;
  }
}

// Paired recurrence, weight-RESIDENT version. Grid = 16 x 512; active bid 0..3
// (half 0) and 8..11 (half 1); pair {g, g+8}. Block holds W_hh rows
// [half*256, +256): 8 waves x 32 cols -> 128 weight VGPRs/wave (+ ~50 others
// = ~180 < the 256/wave cap of an 8-wave block — residency is FEASIBLE here,
// unlike the single-CU variants where W_hh = the whole register file).
// h halves exchanged per step via relaxed agent-scope atomics in a 4-slot
// ring + monotone flag (r5-proven protocol; depth-4 safe since partner
// consumes slot t at its step t+1 and we reuse at t+4 only after seeing
// flag >= t+3). No cache-wide fences.
__global__ __launch_bounds__(512, 1) void rnn_pair_kernel(
    const _Float16* __restrict__ Whh, const _Float16* __restrict__ xwf,
    _Float16* __restrict__ hplain, unsigned int* __restrict__ ring,
    int* __restrict__ flags) {
  const int bid = blockIdx.x;
  int g, half;
  if (bid < 4)                   { g = bid;     half = 0; }
  else if (bid >= 8 && bid < 12) { g = bid - 8; half = 1; }
  else return;

  const int tid = threadIdx.x, wv = tid >> 6, lane = tid & 63;
  const int l15 = lane & 15, quad = lane >> 4;
  const int bb = g * 16;
  const int nloc = wv * 32;                 // within own half [0,256)
  const int nabs = half * 256 + nloc;

  __shared__ _Float16 hbuf[2][16][520];

  // Register-resident W_hh slice: B[k=quad*8+j][n=l15].
  u32x4 Bw[2][16];
#pragma unroll
  for (int tile = 0; tile < 2; ++tile)
#pragma unroll
    for (int kc = 0; kc < 16; ++kc)
      Bw[tile][kc] = *(const u32x4*)&Whh[(size_t)(nabs + tile * 16 + l15) * 512 + kc * 32 + quad * 8];
#pragma unroll
  for (int tile = 0; tile < 2; ++tile)
#pragma unroll
    for (int kc = 0; kc < 16; ++kc)
      asm volatile("" : "+v"(Bw[tile][kc]));

  int* myflag = flags + (g * 2 + half) * 64;
  int* pflag  = flags + (g * 2 + (1 - half)) * 64;
  unsigned int* myring = ring + (size_t)(g * 2 + half) * 4 * 2048;
  unsigned int* pring  = ring + (size_t)(g * 2 + (1 - half)) * 4 * 2048;
  const int kc_lo = half * 8;        // k-chunks this block produces
  const int kc_ro = (1 - half) * 8;  // k-chunks from partner
  const int pbase = (1 - half) * 256;

  // xw prefetch for t=0
  const _Float16* xwb = xwf + (size_t)(nabs + l15) * 64 + bb + quad * 4;
  u32x2 pf[2];
#pragma unroll
  for (int tile = 0; tile < 2; ++tile)
    pf[tile] = *(const u32x2*)(xwb + (size_t)tile * 16 * 64);

  for (int t = 0; t < T_SEQ; ++t) {
    const int p = (t - 1) & 1;

    // 1. coalesced store of own-half h_{t-1} rows from hbuf[p] (full slack)
    if (t > 0) {
      const int br = tid >> 5, c8 = (tid & 31) * 8;
      u32x4 v = *(const u32x4*)&hbuf[p][br][half * 256 + c8];
      *(u32x4*)&hplain[(size_t)((t - 1) * 64 + bb + br) * 512 + half * 256 + c8] = v;
    }

    // 2. acc init from prefetched xw; issue prefetch t+1
    f32x4 acc[2];
#pragma unroll
    for (int tile = 0; tile < 2; ++tile) {
      u32x2 pk = pf[tile];
      acc[tile][0] = (float)u2h((unsigned short)(pk.x & 0xFFFFu));
      acc[tile][1] = (float)u2h((unsigned short)(pk.x >> 16));
      acc[tile][2] = (float)u2h((unsigned short)(pk.y & 0xFFFFu));
      acc[tile][3] = (float)u2h((unsigned short)(pk.y >> 16));
    }
    if (t + 1 < T_SEQ) {
      const _Float16* nx = xwb + (size_t)(t + 1) * 32768;
#pragma unroll
      for (int tile = 0; tile < 2; ++tile)
        pf[tile] = *(const u32x2*)(nx + (size_t)tile * 16 * 64);
    }

    if (t > 0) {
      // 3. local-K MFMAs (own half of h_{t-1} already in LDS)
#pragma unroll
      for (int k = 0; k < 8; ++k) {
        const int kc = kc_lo + k;
        f16x8 a = *(const f16x8*)&hbuf[p][l15][kc * 32 + quad * 8];
        acc[0] = __builtin_amdgcn_mfma_f32_16x16x32_f16(
            a, __builtin_bit_cast(f16x8, Bw[0][kc]), acc[0], 0, 0, 0);
        acc[1] = __builtin_amdgcn_mfma_f32_16x16x32_f16(
            a, __builtin_bit_cast(f16x8, Bw[1][kc]), acc[1], 0, 0, 0);
      }
      // 4. wait for partner's h_{t-1}, pull 8 KB, unpack to LDS
      while (__hip_atomic_load(pflag, __ATOMIC_RELAXED, __HIP_MEMORY_SCOPE_AGENT) < t)
        __builtin_amdgcn_s_sleep(1);
      __atomic_signal_fence(__ATOMIC_ACQUIRE);
      {
        const int c = tid >> 1, b0 = (tid & 1) * 8;
        const unsigned long long* src = (const unsigned long long*)
            (pring + (size_t)((t - 1) & 3) * 2048) + (size_t)c * 4 + (tid & 1) * 2;
        unsigned long long v0 = __hip_atomic_load(src + 0, __ATOMIC_RELAXED, __HIP_MEMORY_SCOPE_AGENT);
        unsigned long long v1 = __hip_atomic_load(src + 1, __ATOMIC_RELAXED, __HIP_MEMORY_SCOPE_AGENT);
#pragma unroll
        for (int i = 0; i < 4; ++i)
          hbuf[p][b0 + i][pbase + c] = u2h((unsigned short)(v0 >> (16 * i)));
#pragma unroll
        for (int i = 0; i < 4; ++i)
          hbuf[p][b0 + 4 + i][pbase + c] = u2h((unsigned short)(v1 >> (16 * i)));
      }
      __syncthreads();   // barrier A: partner half visible
      // 6. remote-K MFMAs
#pragma unroll
      for (int k = 0; k < 8; ++k) {
        const int kc = kc_ro + k;
        f16x8 a = *(const f16x8*)&hbuf[p][l15][kc * 32 + quad * 8];
        acc[0] = __builtin_amdgcn_mfma_f32_16x16x32_f16(
            a, __builtin_bit_cast(f16x8, Bw[0][kc]), acc[0], 0, 0, 0);
        acc[1] = __builtin_amdgcn_mfma_f32_16x16x32_f16(
            a, __builtin_bit_cast(f16x8, Bw[1][kc]), acc[1], 0, 0, 0);
      }
    }

    // 7-8. tanh; write own cols to hbuf[next] + ring (reg-direct, r5 layout)
    const int pn = t & 1;
    _Float16 hv[8];
#pragma unroll
    for (int tile = 0; tile < 2; ++tile)
#pragma unroll
      for (int r = 0; r < 4; ++r)
        hv[tile * 4 + r] = (_Float16)fast_tanh(acc[tile][r]);
#pragma unroll
    for (int tile = 0; tile < 2; ++tile)
#pragma unroll
      for (int r = 0; r < 4; ++r)
        hbuf[pn][quad * 4 + r][nabs + tile * 16 + l15] = hv[tile * 4 + r];
    unsigned int* dstr = myring + (size_t)(t & 3) * 2048;
#pragma unroll
    for (int tile = 0; tile < 2; ++tile)
#pragma unroll
      for (int rp = 0; rp < 2; ++rp) {
        unsigned int pk = ((unsigned int)h2u(hv[tile * 4 + rp * 2 + 1]) << 16) |
                          (unsigned int)h2u(hv[tile * 4 + rp * 2]);
        int idxu = (nloc + tile * 16 + l15) * 8 + quad * 2 + rp;
        __hip_atomic_store(dstr + idxu, pk, __ATOMIC_RELAXED, __HIP_MEMORY_SCOPE_AGENT);
      }
    __syncthreads();   // barrier B: drains all waves' stores (vmcnt) + LDS
    if (tid == 0)
      __hip_atomic_store(myflag, t + 1, __ATOMIC_RELEASE, __HIP_MEMORY_SCOPE_AGENT);
  }

  // store h_{T-1} own half
  {
    const int p = (T_SEQ - 1) & 1;
    const int br = tid >> 5, c8 = (tid & 31) * 8;
    u32x4 v = *(const u32x4*)&hbuf[p][br][half * 256 + c8];
    *(u32x4*)&hplain[(size_t)((T_SEQ - 1) * 64 + bb + br) * 512 + half * 256 + c8] = v;
  }
}

// logits[b][t][v] = h1[t*64+b][:] . Why[v][:] + by[v].  Grid 512 x 256.
__global__ __launch_bounds__(256) void logits_kernel(
    const _Float16* __restrict__ h1, const _Float16* __restrict__ Why,
    const float* __restrict__ by, float* __restrict__ out) {
  const int t = blockIdx.x;
  const int wv = threadIdx.x >> 6, lane = threadIdx.x & 63;
  const int l15 = lane & 15, quad = lane >> 4, bb = wv * 16;
  f32x4 acc[8];
#pragma unroll
  for (int vt = 0; vt < 8; ++vt) { float bv = by[vt * 16 + l15]; acc[vt] = {bv, bv, bv, bv}; }
#pragma unroll
  for (int kc = 0; kc < 16; ++kc) {
    f16x8 a = *(const f16x8*)&h1[(size_t)(t * 64 + bb + l15) * 512 + kc * 32 + quad * 8];
#pragma unroll
    for (int vt = 0; vt < 8; ++vt) {
      f16x8 b = *(const f16x8*)&Why[(size_t)(vt * 16 + l15) * 512 + kc * 32 + quad * 8];
      acc[vt] = __builtin_amdgcn_mfma_f32_16x16x32_f16(a, b, acc[vt], 0, 0, 0);
    }
  }
#pragma unroll
  for (int vt = 0; vt < 8; ++vt)
#pragma unroll
    for (int r = 0; r < 4; ++r)
      out[((size_t)(bb + quad * 4 + r) * 512 + t) * 128 + vt * 16 + l15] = acc[vt][r];
}

__global__ void hlast_kernel(const _Float16* __restrict__ h0,
                             const _Float16* __restrict__ h1,
                             float* __restrict__ out) {
  const size_t LOG = (size_t)BATCH * T_SEQ * VOC;
  const size_t HL = (size_t)BATCH * HID;
  const size_t base = (size_t)(T_SEQ - 1) * BATCH * HID;
  int tid = blockIdx.x * 256 + threadIdx.x;
  if (tid < (int)HL) {
    out[LOG + tid]      = (float)h0[base + tid];
    out[LOG + HL + tid] = (float)h1[base + tid];
  }
}

extern "C" void kernel_launch(void* const* d_in, const int* in_sizes, int n_in,
                              void* d_out, int out_size, void* d_ws, size_t ws_size,
                              hipStream_t stream) {
  const int* x = (const int*)d_in[0];
  float* out = (float*)d_out;
  char* ws = (char*)d_ws;
  int* flags = (int*)(ws + OFF_FLAGS);
  unsigned int* ring = (unsigned int*)(ws + OFF_RING);
  _Float16* arena = (_Float16*)(ws + OFF_ARENA);
  _Float16* xw0f = (_Float16*)(ws + OFF_XW0);
  _Float16* xw1f = (_Float16*)(ws + OFF_XW1);
  _Float16* h0p  = (_Float16*)(ws + OFF_H0P);
  _Float16* h1p  = (_Float16*)(ws + OFF_H1P);

  canon_kernel<<<512, 256, 0, stream>>>(
      (const float*)d_in[1], (const float*)d_in[2], (const float*)d_in[3],
      (const float*)d_in[5], (const float*)d_in[6], (const float*)d_in[8],
      arena, flags);

  xw0_kernel<<<dim3(512, 8), 256, 0, stream>>>(
      x, arena + AOFF_EMB, arena + AOFF_WXH0, (const float*)d_in[4], xw0f);

  rnn_pair_kernel<<<16, 512, 0, stream>>>(
      arena + AOFF_WHH0, xw0f, h0p, ring, flags);

  xw1_kernel<<<dim3(512, 16), 256, 0, stream>>>(
      h0p, arena + AOFF_WXH1, (const float*)d_in[7], xw1f);

  rnn_pair_kernel<<<16, 512, 0, stream>>>(
      arena + AOFF_WHH1, xw1f, h1p, ring + 65536, flags + 8 * 64);

  logits_kernel<<<512, 256, 0, stream>>>(
      h1p, arena + AOFF_WHY, (const float*)d_in[9], out);

  hlast_kernel<<<(BATCH * HID + 255) / 256, 256, 0, stream>>>(h0p, h1p, out);
}

// Round 10
// 3191.875 us; speedup vs baseline: 3.1299x; 3.1299x over previous
//
#include <hip/hip_runtime.h>
#include <hip/hip_fp16.h>

typedef _Float16 f16x8 __attribute__((ext_vector_type(8)));
typedef float f32x4 __attribute__((ext_vector_type(4)));
typedef unsigned int u32x4 __attribute__((ext_vector_type(4)));
typedef unsigned int u32x2 __attribute__((ext_vector_type(2)));
typedef unsigned long long u64;

static constexpr int T_SEQ = 512;
static constexpr int BATCH = 64;
static constexpr int HID   = 512;
static constexpr int VOC   = 128;

// ---- fp16 arena element offsets ----
static constexpr int AOFF_EMB  = 0;        // 128*256
static constexpr int AOFF_WXH0 = 32768;    // 512*256
static constexpr int AOFF_WHH0 = 163840;   // 512*512
static constexpr int AOFF_WXH1 = 425984;   // 512*512
static constexpr int AOFF_WHH1 = 688128;   // 512*512
static constexpr int AOFF_WHY  = 950272;   // 128*512
static constexpr int ATOT      = 1015808;

// ---- ws byte offsets ----
static constexpr size_t OFF_FLAGS = 0;                    // 2*16 regions * 64 ints
static constexpr size_t OFF_RING  = 16384;                // 2 * 32768 u64 = 512 KB
static constexpr size_t OFF_ARENA = 1u << 20;
static constexpr size_t PLANE_B   = (size_t)T_SEQ * BATCH * HID * 2;  // 32 MB
static constexpr size_t OFF_XW0   = 4u << 20;
static constexpr size_t OFF_XW1   = OFF_XW0 + PLANE_B;
static constexpr size_t OFF_H0A   = OFF_XW1 + PLANE_B;    // A-frag layout [t][g][kc][lane][8]
static constexpr size_t OFF_H1A   = OFF_H0A + PLANE_B;    // ends ~132 MB

__device__ __forceinline__ unsigned short h2u(_Float16 h) {
  union { _Float16 h; unsigned short u; } c; c.h = h; return c.u;
}
__device__ __forceinline__ _Float16 u2h(unsigned short u) {
  union { unsigned short u; _Float16 h; } c; c.u = u; return c.h;
}
__device__ __forceinline__ float fast_tanh(float x) {
  float e = __expf(2.0f * x);
  return 1.0f - 2.0f * __builtin_amdgcn_rcpf(e + 1.0f);
}

// fp32 params -> fp16 arena; zero flags (2 layers x 16 regions x 64 ints).
__global__ __launch_bounds__(256) void canon_kernel(
    const float* p0, const float* p1, const float* p2, const float* p3,
    const float* p4, const float* p5, _Float16* __restrict__ dst,
    int* __restrict__ flags) {
  if (blockIdx.x == 0)
    for (int i = threadIdx.x; i < 2 * 16 * 64; i += 256) flags[i] = 0;
  const float* srcs[6] = {p0, p1, p2, p3, p4, p5};
  const int ns[6] = {32768, 131072, 262144, 262144, 262144, 65536};
  for (int i = blockIdx.x * 256 + threadIdx.x; i < ATOT; i += gridDim.x * 256) {
    int off = i, s = 0;
    while (off >= ns[s]) { off -= ns[s]; ++s; }
    dst[i] = (_Float16)srcs[s][off];
  }
}

// xwf0[t][n][b] = emb[x[b,t]][:] . Wxh0[n][:] + bh0[n].  Grid (512, 8) x 256.
__global__ __launch_bounds__(256) void xw0_kernel(
    const int* __restrict__ x, const _Float16* __restrict__ emb,
    const _Float16* __restrict__ Wxh, const float* __restrict__ bh,
    _Float16* __restrict__ xwf) {
  __shared__ _Float16 Bs[64][264];
  const int t = blockIdx.x, n0 = blockIdx.y * 64, tid = threadIdx.x;
#pragma unroll
  for (int rep = 0; rep < 8; ++rep) {
    int flat = rep * 256 + tid;
    int row = flat >> 5, c8 = flat & 31;
    *(f16x8*)&Bs[row][c8 * 8] = *(const f16x8*)&Wxh[(size_t)(n0 + row) * 256 + c8 * 8];
  }
  __syncthreads();
  const int wv = tid >> 6, lane = tid & 63, l15 = lane & 15, quad = lane >> 4;
  const int b = wv * 16 + l15;
  const int idx = x[b * 512 + t];
  f32x4 acc[4];
#pragma unroll
  for (int nt = 0; nt < 4; ++nt) { float bv = bh[n0 + nt * 16 + l15]; acc[nt] = {bv, bv, bv, bv}; }
#pragma unroll
  for (int kc = 0; kc < 8; ++kc) {
    f16x8 a = *(const f16x8*)&emb[(size_t)idx * 256 + kc * 32 + quad * 8];
#pragma unroll
    for (int nt = 0; nt < 4; ++nt) {
      f16x8 bf = *(const f16x8*)&Bs[nt * 16 + l15][kc * 32 + quad * 8];
      acc[nt] = __builtin_amdgcn_mfma_f32_16x16x32_f16(a, bf, acc[nt], 0, 0, 0);
    }
  }
#pragma unroll
  for (int nt = 0; nt < 4; ++nt) {
    unsigned int lo = (unsigned int)h2u((_Float16)acc[nt][0]) |
                      ((unsigned int)h2u((_Float16)acc[nt][1]) << 16);
    unsigned int hi = (unsigned int)h2u((_Float16)acc[nt][2]) |
                      ((unsigned int)h2u((_Float16)acc[nt][3]) << 16);
    u32x2 pk = {lo, hi};
    *(u32x2*)&xwf[(size_t)t * 32768 + (size_t)(n0 + nt * 16 + l15) * 64 + wv * 16 + quad * 4] = pk;
  }
}

// xwf1[t][n][b] = h0[t,b][:] . Wxh1[n][:] + bh1[n]; h0 read in A-frag layout.
// Grid (512, 16) x 256.
__global__ __launch_bounds__(256) void xw1_kernel(
    const _Float16* __restrict__ h0A, const _Float16* __restrict__ Wxh,
    const float* __restrict__ bh, _Float16* __restrict__ xwf) {
  __shared__ _Float16 Bs[32][520];
  const int t = blockIdx.x, n0 = blockIdx.y * 32, tid = threadIdx.x;
#pragma unroll
  for (int rep = 0; rep < 8; ++rep) {
    int flat = rep * 256 + tid;
    int row = flat >> 6, c8 = flat & 63;
    *(f16x8*)&Bs[row][c8 * 8] = *(const f16x8*)&Wxh[(size_t)(n0 + row) * 512 + c8 * 8];
  }
  __syncthreads();
  const int wv = tid >> 6, lane = tid & 63, l15 = lane & 15, quad = lane >> 4;
  f32x4 acc[2];
#pragma unroll
  for (int nt = 0; nt < 2; ++nt) { float bv = bh[n0 + nt * 16 + l15]; acc[nt] = {bv, bv, bv, bv}; }
#pragma unroll
  for (int kc = 0; kc < 16; ++kc) {
    // identity A-frag load: group g = wv (batches 16wv..16wv+16)
    f16x8 a = *(const f16x8*)&h0A[(((size_t)t * 4 + wv) * 16 + kc) * 512 + lane * 8];
#pragma unroll
    for (int nt = 0; nt < 2; ++nt) {
      f16x8 bf = *(const f16x8*)&Bs[nt * 16 + l15][kc * 32 + quad * 8];
      acc[nt] = __builtin_amdgcn_mfma_f32_16x16x32_f16(a, bf, acc[nt], 0, 0, 0);
    }
  }
#pragma unroll
  for (int nt = 0; nt < 2; ++nt) {
    unsigned int lo = (unsigned int)h2u((_Float16)acc[nt][0]) |
                      ((unsigned int)h2u((_Float16)acc[nt][1]) << 16);
    unsigned int hi = (unsigned int)h2u((_Float16)acc[nt][2]) |
                      ((unsigned int)h2u((_Float16)acc[nt][3]) << 16);
    u32x2 pk = {lo, hi};
    *(u32x2*)&xwf[(size_t)t * 32768 + (size_t)(n0 + nt * 16 + l15) * 64 + wv * 16 + quad * 4] = pk;
  }
}

// Quad recurrence: grid 16 x 512. Block b: group g=b&3 (batches 16g..+16),
// quarter q=b>>2 (cols 128q..+128). Wave owns 16 cols -> 64 weight VGPRs
// (allocator-friendly; zero weight streaming after the initial load).
// h in 16KB LDS A-frag buffer [kc][lane][8]; producers stage tanh output
// pre-transposed so ring pack/unpack and all A-loads are identity/conflict-free.
// Exchange: relaxed agent-atomic 4-slot ring + monotone flags (r5/r8-proven).
__global__ __launch_bounds__(512, 1) void rnn_quad_kernel(
    const _Float16* __restrict__ Whh,
    const _Float16* __restrict__ xwf,
    _Float16* __restrict__ hA,          // [t][g][kc][lane][8] A-frag dump (by q0)
    u64* __restrict__ ring,             // [(g*4+q)][slot][512]
    int* __restrict__ flags)            // [(g*4+q)*64]
{
  const int bidx = blockIdx.x, g = bidx & 3, q = bidx >> 2;
  const int tid = threadIdx.x, lane = tid & 63, wv = tid >> 6;
  const int l15 = lane & 15, quad = lane >> 4;
  const int n0 = q * 128 + wv * 16;

  __shared__ _Float16 alds[16 * 512];
  u64* aldsu = (u64*)alds;

  // 64 weight VGPRs/wave: B[k=kc*32+quad*8+j][n=l15] = Whh[n0+l15][k]
  u32x4 Bw[16];
#pragma unroll
  for (int kc = 0; kc < 16; ++kc)
    Bw[kc] = *(const u32x4*)&Whh[(size_t)(n0 + l15) * 512 + kc * 32 + quad * 8];
#pragma unroll
  for (int kc = 0; kc < 16; ++kc)
    asm volatile("" : "+v"(Bw[kc]));

  int* pflag[3];
  u64* pring[3];
  int pquar[3];
  {
    int pi = 0;
    for (int qq = 0; qq < 4; ++qq)
      if (qq != q) {
        pflag[pi] = flags + (g * 4 + qq) * 64;
        pring[pi] = ring + (size_t)(g * 4 + qq) * 4 * 512;
        pquar[pi] = qq;
        ++pi;
      }
  }
  int* myflag = flags + (g * 4 + q) * 64;
  u64* myring = ring + (size_t)(g * 4 + q) * 4 * 512;

  const _Float16* xwb = xwf + (size_t)(n0 + l15) * 64 + g * 16 + quad * 4;
  u32x2 pfx = *(const u32x2*)xwb;

  for (int t = 0; t < T_SEQ; ++t) {
    f32x4 acc;
    acc[0] = (float)u2h((unsigned short)(pfx.x & 0xFFFFu));
    acc[1] = (float)u2h((unsigned short)(pfx.x >> 16));
    acc[2] = (float)u2h((unsigned short)(pfx.y & 0xFFFFu));
    acc[3] = (float)u2h((unsigned short)(pfx.y >> 16));
    if (t + 1 < T_SEQ) pfx = *(const u32x2*)(xwb + (size_t)(t + 1) * 32768);

    if (t > 0) {
      // wait for partners' h_{t-1} (flag >= t); loads below are control-dep ordered
      while (__hip_atomic_load(pflag[0], __ATOMIC_RELAXED, __HIP_MEMORY_SCOPE_AGENT) < t ||
             __hip_atomic_load(pflag[1], __ATOMIC_RELAXED, __HIP_MEMORY_SCOPE_AGENT) < t ||
             __hip_atomic_load(pflag[2], __ATOMIC_RELAXED, __HIP_MEMORY_SCOPE_AGENT) < t)
        __builtin_amdgcn_s_sleep(1);
      const int slot = (t - 1) & 3;
#pragma unroll
      for (int p = 0; p < 3; ++p) {
        u64 v = __hip_atomic_load(pring[p] + (size_t)slot * 512 + tid,
                                  __ATOMIC_RELAXED, __HIP_MEMORY_SCOPE_AGENT);
        aldsu[pquar[p] * 512 + tid] = v;
      }
      __syncthreads();  // bar_A: alds(t-1) complete

      if (q == 0) {     // dump h_{t-1} fragplane (16 KB) for xw1/logits/hlast
        u64* dst = (u64*)hA + ((size_t)(t - 1) * 4 + g) * 2048;   // FIX: plane = 2048 u64
#pragma unroll
        for (int i = 0; i < 4; ++i)
          dst[tid + 512 * i] = aldsu[tid + 512 * i];
      }

#pragma unroll
      for (int kc = 0; kc < 16; ++kc) {
        f16x8 a = *(const f16x8*)&alds[kc * 512 + lane * 8];
        acc = __builtin_amdgcn_mfma_f32_16x16x32_f16(
            a, __builtin_bit_cast(f16x8, Bw[kc]), acc, 0, 0, 0);
      }
      __syncthreads();  // bar1: alds reads done before overwrite
    }

    // tanh + stage own cols of h_t into alds in A-frag order
    {
      const int n = n0 + l15;
      const int kc = n >> 5, qd = (n >> 3) & 3, j = n & 7;
#pragma unroll
      for (int r = 0; r < 4; ++r)
        alds[kc * 512 + (qd * 16 + quad * 4 + r) * 8 + j] = (_Float16)fast_tanh(acc[r]);
    }
    __syncthreads();    // bar2: staging visible
    {
      u64 v = aldsu[q * 512 + tid];
      __hip_atomic_store(myring + (size_t)(t & 3) * 512 + tid, v,
                         __ATOMIC_RELAXED, __HIP_MEMORY_SCOPE_AGENT);
    }
    __syncthreads();    // bar3: all waves' ring stores (+ q0 dump) drained
    if (tid == 0)
      __hip_atomic_store(myflag, t + 1, __ATOMIC_RELEASE, __HIP_MEMORY_SCOPE_AGENT);
  }

  // epilogue: q0 assembles and dumps h_{T-1}
  if (q == 0) {
    while (__hip_atomic_load(pflag[0], __ATOMIC_RELAXED, __HIP_MEMORY_SCOPE_AGENT) < T_SEQ ||
           __hip_atomic_load(pflag[1], __ATOMIC_RELAXED, __HIP_MEMORY_SCOPE_AGENT) < T_SEQ ||
           __hip_atomic_load(pflag[2], __ATOMIC_RELAXED, __HIP_MEMORY_SCOPE_AGENT) < T_SEQ)
      __builtin_amdgcn_s_sleep(1);
    const int slot = (T_SEQ - 1) & 3;
#pragma unroll
    for (int p = 0; p < 3; ++p) {
      u64 v = __hip_atomic_load(pring[p] + (size_t)slot * 512 + tid,
                                __ATOMIC_RELAXED, __HIP_MEMORY_SCOPE_AGENT);
      aldsu[pquar[p] * 512 + tid] = v;
    }
    __syncthreads();
    u64* dst = (u64*)hA + ((size_t)(T_SEQ - 1) * 4 + g) * 2048;   // FIX: plane = 2048 u64
#pragma unroll
    for (int i = 0; i < 4; ++i)
      dst[tid + 512 * i] = aldsu[tid + 512 * i];
  }
}

// logits[b][t][v] = h1[t,b][:] . Why[v][:] + by[v]; h1 in A-frag layout. Grid 512 x 256.
__global__ __launch_bounds__(256) void logits_kernel(
    const _Float16* __restrict__ h1A, const _Float16* __restrict__ Why,
    const float* __restrict__ by, float* __restrict__ out) {
  const int t = blockIdx.x;
  const int wv = threadIdx.x >> 6, lane = threadIdx.x & 63;
  const int l15 = lane & 15, quad = lane >> 4, bb = wv * 16;
  f32x4 acc[8];
#pragma unroll
  for (int vt = 0; vt < 8; ++vt) { float bv = by[vt * 16 + l15]; acc[vt] = {bv, bv, bv, bv}; }
#pragma unroll
  for (int kc = 0; kc < 16; ++kc) {
    f16x8 a = *(const f16x8*)&h1A[(((size_t)t * 4 + wv) * 16 + kc) * 512 + lane * 8];
#pragma unroll
    for (int vt = 0; vt < 8; ++vt) {
      f16x8 b = *(const f16x8*)&Why[(size_t)(vt * 16 + l15) * 512 + kc * 32 + quad * 8];
      acc[vt] = __builtin_amdgcn_mfma_f32_16x16x32_f16(a, b, acc[vt], 0, 0, 0);
    }
  }
#pragma unroll
  for (int vt = 0; vt < 8; ++vt)
#pragma unroll
    for (int r = 0; r < 4; ++r)
      out[((size_t)(bb + quad * 4 + r) * 512 + t) * 128 + vt * 16 + l15] = acc[vt][r];
}

// h_last from A-frag dumps at t=511. One element each per layer.
__global__ void hlast_kernel(const _Float16* __restrict__ h0A,
                             const _Float16* __restrict__ h1A,
                             float* __restrict__ out) {
  const size_t LOG = (size_t)BATCH * T_SEQ * VOC;
  const size_t HL = (size_t)BATCH * HID;
  int tid = blockIdx.x * 256 + threadIdx.x;
  if (tid < (int)HL) {
    const int b = tid >> 9, n = tid & 511;
    const int gg = b >> 4, m = b & 15;
    const int kc = n >> 5, qd = (n >> 3) & 3, j = n & 7;
    const size_t idx = (((size_t)(T_SEQ - 1) * 4 + gg) * 16 + kc) * 512 + (qd * 16 + m) * 8 + j;
    out[LOG + tid]      = (float)h0A[idx];
    out[LOG + HL + tid] = (float)h1A[idx];
  }
}

extern "C" void kernel_launch(void* const* d_in, const int* in_sizes, int n_in,
                              void* d_out, int out_size, void* d_ws, size_t ws_size,
                              hipStream_t stream) {
  const int* x = (const int*)d_in[0];
  float* out = (float*)d_out;
  char* ws = (char*)d_ws;
  int* flags = (int*)(ws + OFF_FLAGS);
  u64* ring = (u64*)(ws + OFF_RING);      // 2 layers x 32768 u64
  _Float16* arena = (_Float16*)(ws + OFF_ARENA);
  _Float16* xw0f = (_Float16*)(ws + OFF_XW0);
  _Float16* xw1f = (_Float16*)(ws + OFF_XW1);
  _Float16* h0A  = (_Float16*)(ws + OFF_H0A);
  _Float16* h1A  = (_Float16*)(ws + OFF_H1A);

  canon_kernel<<<512, 256, 0, stream>>>(
      (const float*)d_in[1], (const float*)d_in[2], (const float*)d_in[3],
      (const float*)d_in[5], (const float*)d_in[6], (const float*)d_in[8],
      arena, flags);

  xw0_kernel<<<dim3(512, 8), 256, 0, stream>>>(
      x, arena + AOFF_EMB, arena + AOFF_WXH0, (const float*)d_in[4], xw0f);

  rnn_quad_kernel<<<16, 512, 0, stream>>>(
      arena + AOFF_WHH0, xw0f, h0A, ring, flags);

  xw1_kernel<<<dim3(512, 16), 256, 0, stream>>>(
      h0A, arena + AOFF_WXH1, (const float*)d_in[7], xw1f);

  rnn_quad_kernel<<<16, 512, 0, stream>>>(
      arena + AOFF_WHH1, xw1f, h1A, ring + 32768, flags + 16 * 64);

  logits_kernel<<<512, 256, 0, stream>>>(
      h1A, arena + AOFF_WHY, (const float*)d_in[9], out);

  hlast_kernel<<<(BATCH * HID + 255) / 256, 256, 0, stream>>>(h0A, h1A, out);
}